// Round 1
// baseline (379.071 us; speedup 1.0000x reference)
//
#include <hip/hip_runtime.h>
#include <hip/hip_bf16.h>

#define BB 8
#define CC 512
#define SS 64
#define TT 128
#define DD 256
#define PP 8
#define BS (BB*SS)            // 512
#define NSTAT (BB*CC*SS)      // 262144
#define EPSV 1e-5f

typedef float f32x4 __attribute__((ext_vector_type(4)));
typedef __bf16 bf16x8 __attribute__((ext_vector_type(8)));

__device__ __forceinline__ unsigned short f2bf(float f) {
  unsigned u = __float_as_uint(f);
  u += 0x7FFFu + ((u >> 16) & 1u);
  return (unsigned short)(u >> 16);
}

// ---------------- K1: BN stats (per-t sum/sumsq) + per-(b,s) column sums over c ----
__global__ __launch_bounds__(256) void k1_stats(const float* __restrict__ x,
    float* __restrict__ sumt, float* __restrict__ sumsq, float* __restrict__ colsum) {
  int bs = blockIdx.x; int b = bs >> 6, s = bs & 63;
  const float* xb = x + ((size_t)b * CC * SS + s) * TT;
  int tid = threadIdx.x;
  int t4 = tid & 31, coff = tid >> 5;
  float cs0=0,cs1=0,cs2=0,cs3=0, ss0=0,ss1=0,ss2=0,ss3=0;
  #pragma unroll 4
  for (int c = coff; c < CC; c += 8) {
    float4 v = *reinterpret_cast<const float4*>(xb + (size_t)c*(SS*TT) + t4*4);
    cs0 += v.x; cs1 += v.y; cs2 += v.z; cs3 += v.w;
    ss0 += v.x*v.x; ss1 += v.y*v.y; ss2 += v.z*v.z; ss3 += v.w*v.w;
  }
  __shared__ float4 redC[256];
  __shared__ float4 redS[256];
  redC[tid] = make_float4(cs0,cs1,cs2,cs3);
  redS[tid] = make_float4(ss0,ss1,ss2,ss3);
  __syncthreads();
  if (tid < 32) {
    #pragma unroll
    for (int j = 1; j < 8; j++) {
      float4 a = redC[tid + j*32], bq = redS[tid + j*32];
      cs0+=a.x; cs1+=a.y; cs2+=a.z; cs3+=a.w;
      ss0+=bq.x; ss1+=bq.y; ss2+=bq.z; ss3+=bq.w;
    }
    *reinterpret_cast<float4*>(colsum + (size_t)bs*TT + tid*4) = make_float4(cs0,cs1,cs2,cs3);
    atomicAdd(&sumt[tid*4+0], cs0); atomicAdd(&sumt[tid*4+1], cs1);
    atomicAdd(&sumt[tid*4+2], cs2); atomicAdd(&sumt[tid*4+3], cs3);
    atomicAdd(&sumsq[tid*4+0], ss0); atomicAdd(&sumsq[tid*4+1], ss1);
    atomicAdd(&sumsq[tid*4+2], ss2); atomicAdd(&sumsq[tid*4+3], ss3);
  }
}

// ---------------- K2: route 1 -> a1, W1 (fp32 out + bf16 ws), b1 --------------------
__global__ __launch_bounds__(256) void k2_route1(
    const float* __restrict__ sumt, const float* __restrict__ sumsq,
    const float* __restrict__ colsum, const float* __restrict__ gamma,
    const float* __restrict__ beta, const float* __restrict__ keys1,
    const float* __restrict__ Wp1, const float* __restrict__ bp1,
    float* __restrict__ w1out, unsigned short* __restrict__ w1bf,
    float* __restrict__ b1) {
  int bs = blockIdx.x, tid = threadIdx.x;
  __shared__ float a1s[PP];
  if (tid < 64) {
    float pv0, pv1;
    {
      int t = tid;
      float m = sumt[t] * (1.f/NSTAT);
      float var = sumsq[t]*(1.f/NSTAT) - m*m;
      float g = gamma[t] * rsqrtf(var + EPSV);
      pv0 = (colsum[(size_t)bs*TT + t]*(1.f/CC) - m)*g + beta[t];
    }
    {
      int t = tid + 64;
      float m = sumt[t] * (1.f/NSTAT);
      float var = sumsq[t]*(1.f/NSTAT) - m*m;
      float g = gamma[t] * rsqrtf(var + EPSV);
      pv1 = (colsum[(size_t)bs*TT + t]*(1.f/CC) - m)*g + beta[t];
    }
    float ssq = pv0*pv0 + pv1*pv1;
    #pragma unroll
    for (int off=32; off; off>>=1) ssq += __shfl_xor(ssq, off);
    float pn = sqrtf(ssq) + 1e-8f;
    float lg[PP];
    #pragma unroll
    for (int p=0;p<PP;p++) {
      float k0 = keys1[p*TT + tid], k1 = keys1[p*TT + tid + 64];
      float dot = pv0*k0 + pv1*k1;
      float kn = k0*k0 + k1*k1;
      #pragma unroll
      for (int off=32; off; off>>=1) { dot += __shfl_xor(dot,off); kn += __shfl_xor(kn,off); }
      lg[p] = dot / (pn * (sqrtf(kn) + 1e-8f));
    }
    if (tid == 0) {
      float mx = lg[0];
      #pragma unroll
      for (int p=1;p<PP;p++) mx = fmaxf(mx, lg[p]);
      float se = 0.f, e[PP];
      #pragma unroll
      for (int p=0;p<PP;p++){ e[p] = __expf(lg[p]-mx); se += e[p]; }
      float inv = 1.f/se;
      #pragma unroll
      for (int p=0;p<PP;p++) a1s[p] = e[p]*inv;
    }
  }
  __syncthreads();
  float a[PP];
  #pragma unroll
  for (int p=0;p<PP;p++) a[p]=a1s[p];
  const float4* wp = reinterpret_cast<const float4*>(Wp1);
  float4* wo = reinterpret_cast<float4*>(w1out + (size_t)bs*(DD*TT));
  ushort4* wb = reinterpret_cast<ushort4*>(w1bf + (size_t)bs*(DD*TT));
  for (int i=0;i<32;i++) {
    int idx = tid + i*256;
    float4 accv = make_float4(0.f,0.f,0.f,0.f);
    #pragma unroll
    for (int p=0;p<PP;p++) {
      float4 v = wp[p*8192 + idx];
      accv.x += a[p]*v.x; accv.y += a[p]*v.y; accv.z += a[p]*v.z; accv.w += a[p]*v.w;
    }
    wo[idx] = accv;
    ushort4 o; o.x=f2bf(accv.x); o.y=f2bf(accv.y); o.z=f2bf(accv.z); o.w=f2bf(accv.w);
    wb[idx] = o;
  }
  {
    float bacc = 0.f;
    #pragma unroll
    for (int p=0;p<PP;p++) bacc += a[p]*bp1[p*DD + tid];
    b1[(size_t)bs*DD + tid] = bacc;
  }
}

// ---------------- K3: GEMM1 (Z = relu(BN(x) @ W1^T + b1)) + pooled2 partials --------
__global__ __launch_bounds__(256) void k3_gemm1(
    const float* __restrict__ x, const float* __restrict__ sumt,
    const float* __restrict__ sumsq, const float* __restrict__ gamma,
    const float* __restrict__ beta, const unsigned short* __restrict__ w1bf,
    const float* __restrict__ b1, unsigned short* __restrict__ zbf,
    float* __restrict__ p2acc) {
  int bid = blockIdx.x;
  int bs = bid >> 2, mt = bid & 3;
  int b = bs >> 6, s = bs & 63;
  __shared__ unsigned short lA[128*128];   // 32 KB, row stride 256 B, XOR-swizzled
  __shared__ unsigned short lB[256*128];   // 64 KB, row stride 256 B, XOR-swizzled
  __shared__ float mean_s[TT], g_s[TT], beta_s[TT];
  int tid = threadIdx.x;
  if (tid < TT) {
    float m = sumt[tid]*(1.f/NSTAT);
    float var = sumsq[tid]*(1.f/NSTAT) - m*m;
    mean_s[tid] = m;
    g_s[tid] = gamma[tid]*rsqrtf(var+EPSV);
    beta_s[tid] = beta[tid];
  }
  __syncthreads();
  char* lAc = reinterpret_cast<char*>(lA);
  char* lBc = reinterpret_cast<char*>(lB);
  // stage A (BN fused, fp32 -> bf16)
  const float* xb = x + (((size_t)b*CC + mt*128)*SS + s)*TT;
  #pragma unroll
  for (int i=0;i<16;i++) {
    int flat = tid + i*256;
    int r = flat >> 5, c4 = flat & 31;
    float4 v = *reinterpret_cast<const float4*>(xb + (size_t)r*(SS*TT) + c4*4);
    int t0 = c4*4;
    ushort4 o;
    o.x = f2bf((v.x - mean_s[t0+0])*g_s[t0+0] + beta_s[t0+0]);
    o.y = f2bf((v.y - mean_s[t0+1])*g_s[t0+1] + beta_s[t0+1]);
    o.z = f2bf((v.z - mean_s[t0+2])*g_s[t0+2] + beta_s[t0+2]);
    o.w = f2bf((v.w - mean_s[t0+3])*g_s[t0+3] + beta_s[t0+3]);
    unsigned addr = (unsigned)(r*256) + (((unsigned)(c4*8)) ^ (((unsigned)(r&7))<<4));
    *reinterpret_cast<ushort4*>(lAc + addr) = o;
  }
  // stage B (W1 bf16, 16B chunks)
  const unsigned short* wsrc = w1bf + (size_t)bs*(DD*TT);
  #pragma unroll
  for (int i=0;i<16;i++) {
    int flat = tid + i*256;
    int n = flat >> 4, ch = flat & 15;
    uint4 v = *reinterpret_cast<const uint4*>(wsrc + (size_t)n*TT + ch*8);
    unsigned addr = (unsigned)(n*256) + (((unsigned)(ch*16)) ^ (((unsigned)(n&7))<<4));
    *reinterpret_cast<uint4*>(lBc + addr) = v;
  }
  __syncthreads();
  int wave = tid >> 6, lane = tid & 63;
  int wm = wave >> 1, wn = wave & 1;
  int lr = lane & 15, kg = lane >> 4;
  f32x4 zero = {0.f,0.f,0.f,0.f};
  f32x4 acc[4][8];
  #pragma unroll
  for (int m=0;m<4;m++)
    #pragma unroll
    for (int n=0;n<8;n++) acc[m][n] = zero;
  #pragma unroll
  for (int k0=0;k0<128;k0+=32) {
    bf16x8 af[4], bfr[8];
    #pragma unroll
    for (int m=0;m<4;m++) {
      int row = wm*64 + m*16 + lr;
      unsigned addr = (unsigned)(row*256) + (((unsigned)(k0*2 + kg*16)) ^ (((unsigned)(row&7))<<4));
      af[m] = *reinterpret_cast<const bf16x8*>(lAc + addr);
    }
    #pragma unroll
    for (int n=0;n<8;n++) {
      int row = wn*128 + n*16 + lr;
      unsigned addr = (unsigned)(row*256) + (((unsigned)(k0*2 + kg*16)) ^ (((unsigned)(row&7))<<4));
      bfr[n] = *reinterpret_cast<const bf16x8*>(lBc + addr);
    }
    #pragma unroll
    for (int m=0;m<4;m++)
      #pragma unroll
      for (int n=0;n<8;n++)
        acc[m][n] = __builtin_amdgcn_mfma_f32_16x16x32_bf16(af[m], bfr[n], acc[m][n], 0, 0, 0);
  }
  // epilogue: +b1, relu, store Z bf16, pooled2 partial sums
  const float* b1p = b1 + (size_t)bs*DD;
  unsigned short* zb = zbf + (((size_t)b*CC + mt*128)*SS + s)*DD;
  float* p2p = p2acc + (size_t)bs*DD;
  #pragma unroll
  for (int n=0;n<8;n++) {
    int d = wn*128 + n*16 + lr;
    float bv = b1p[d];
    float csum = 0.f;
    #pragma unroll
    for (int m=0;m<4;m++) {
      int rbase = wm*64 + m*16 + kg*4;
      #pragma unroll
      for (int j=0;j<4;j++) {
        float v = fmaxf(acc[m][n][j] + bv, 0.f);
        zb[(size_t)(rbase+j)*(SS*DD) + d] = f2bf(v);
        csum += v;
      }
    }
    csum += __shfl_xor(csum, 16);
    csum += __shfl_xor(csum, 32);
    if (kg == 0) atomicAdd(&p2p[d], csum);
  }
}

// ---------------- K4: route 2 -> a2, W2 (fp32 out + bf16 ws), b2 --------------------
__global__ __launch_bounds__(256) void k4_route2(
    const float* __restrict__ p2acc, const float* __restrict__ keys2,
    const float* __restrict__ Wp2, const float* __restrict__ bp2,
    float* __restrict__ w2out, unsigned short* __restrict__ w2bf,
    float* __restrict__ b2) {
  int bs = blockIdx.x, tid = threadIdx.x;
  __shared__ float a2s[PP];
  if (tid < 64) {
    float pv[4]; float ssq = 0.f;
    #pragma unroll
    for (int j=0;j<4;j++) {
      int d = tid + 64*j;
      pv[j] = p2acc[(size_t)bs*DD + d] * (1.f/CC);
      ssq += pv[j]*pv[j];
    }
    #pragma unroll
    for (int off=32; off; off>>=1) ssq += __shfl_xor(ssq, off);
    float pn = sqrtf(ssq) + 1e-8f;
    float lg[PP];
    #pragma unroll
    for (int p=0;p<PP;p++) {
      float dot = 0.f, kn = 0.f;
      #pragma unroll
      for (int j=0;j<4;j++) {
        int d = tid + 64*j;
        float kv = keys2[p*DD + d];
        dot += pv[j]*kv; kn += kv*kv;
      }
      #pragma unroll
      for (int off=32; off; off>>=1) { dot += __shfl_xor(dot,off); kn += __shfl_xor(kn,off); }
      lg[p] = dot / (pn * (sqrtf(kn)+1e-8f));
    }
    if (tid == 0) {
      float mx = lg[0];
      #pragma unroll
      for (int p=1;p<PP;p++) mx = fmaxf(mx,lg[p]);
      float se=0.f, e[PP];
      #pragma unroll
      for (int p=0;p<PP;p++){ e[p]=__expf(lg[p]-mx); se+=e[p]; }
      float inv = 1.f/se;
      #pragma unroll
      for (int p=0;p<PP;p++) a2s[p]=e[p]*inv;
    }
  }
  __syncthreads();
  float a[PP];
  #pragma unroll
  for (int p=0;p<PP;p++) a[p]=a2s[p];
  const float4* wp = reinterpret_cast<const float4*>(Wp2);
  float4* wo = reinterpret_cast<float4*>(w2out + (size_t)bs*(TT*DD));
  ushort4* wb = reinterpret_cast<ushort4*>(w2bf + (size_t)bs*(TT*DD));
  for (int i=0;i<32;i++) {
    int idx = tid + i*256;
    float4 accv = make_float4(0.f,0.f,0.f,0.f);
    #pragma unroll
    for (int p=0;p<PP;p++) {
      float4 v = wp[p*8192 + idx];
      accv.x += a[p]*v.x; accv.y += a[p]*v.y; accv.z += a[p]*v.z; accv.w += a[p]*v.w;
    }
    wo[idx] = accv;
    ushort4 o; o.x=f2bf(accv.x); o.y=f2bf(accv.y); o.z=f2bf(accv.z); o.w=f2bf(accv.w);
    wb[idx] = o;
  }
  if (tid < TT) {
    float bacc = 0.f;
    #pragma unroll
    for (int p=0;p<PP;p++) bacc += a[p]*bp2[p*TT + tid];
    b2[(size_t)bs*TT + tid] = bacc;
  }
}

// ---------------- K5: GEMM2 (out = x + Z @ W2^T + b2) -------------------------------
__global__ __launch_bounds__(256) void k5_gemm2(
    const unsigned short* __restrict__ zbf, const unsigned short* __restrict__ w2bf,
    const float* __restrict__ b2, const float* __restrict__ x,
    float* __restrict__ out) {
  int bid = blockIdx.x;
  int bs = bid >> 2, mt = bid & 3;
  int b = bs >> 6, s = bs & 63;
  __shared__ unsigned short lA[128*256];   // 64 KB, row stride 512 B
  __shared__ unsigned short lB[128*256];   // 64 KB, row stride 512 B
  int tid = threadIdx.x;
  char* lAc = reinterpret_cast<char*>(lA);
  char* lBc = reinterpret_cast<char*>(lB);
  const unsigned short* za = zbf + (((size_t)b*CC + mt*128)*SS + s)*DD;
  #pragma unroll
  for (int i=0;i<16;i++) {
    int flat = tid + i*256;
    int r = flat >> 5, ch = flat & 31;
    uint4 v = *reinterpret_cast<const uint4*>(za + (size_t)r*(SS*DD) + ch*8);
    unsigned addr = (unsigned)(r*512) + (((unsigned)(ch*16)) ^ (((unsigned)(r&7))<<4));
    *reinterpret_cast<uint4*>(lAc + addr) = v;
  }
  const unsigned short* wsrc = w2bf + (size_t)bs*(TT*DD);
  #pragma unroll
  for (int i=0;i<16;i++) {
    int flat = tid + i*256;
    int r = flat >> 5, ch = flat & 31;
    uint4 v = *reinterpret_cast<const uint4*>(wsrc + (size_t)flat*8);
    unsigned addr = (unsigned)(r*512) + (((unsigned)(ch*16)) ^ (((unsigned)(r&7))<<4));
    *reinterpret_cast<uint4*>(lBc + addr) = v;
  }
  __syncthreads();
  int wave = tid >> 6, lane = tid & 63;
  int wm = wave >> 1, wn = wave & 1;
  int lr = lane & 15, kg = lane >> 4;
  f32x4 zero = {0.f,0.f,0.f,0.f};
  f32x4 acc[4][4];
  #pragma unroll
  for (int m=0;m<4;m++)
    #pragma unroll
    for (int n=0;n<4;n++) acc[m][n] = zero;
  #pragma unroll
  for (int k0=0;k0<256;k0+=32) {
    bf16x8 af[4], bfr[4];
    #pragma unroll
    for (int m=0;m<4;m++) {
      int row = wm*64 + m*16 + lr;
      unsigned addr = (unsigned)(row*512) + (((unsigned)(k0*2 + kg*16)) ^ (((unsigned)(row&7))<<4));
      af[m] = *reinterpret_cast<const bf16x8*>(lAc + addr);
    }
    #pragma unroll
    for (int n=0;n<4;n++) {
      int row = wn*64 + n*16 + lr;
      unsigned addr = (unsigned)(row*512) + (((unsigned)(k0*2 + kg*16)) ^ (((unsigned)(row&7))<<4));
      bfr[n] = *reinterpret_cast<const bf16x8*>(lBc + addr);
    }
    #pragma unroll
    for (int m=0;m<4;m++)
      #pragma unroll
      for (int n=0;n<4;n++)
        acc[m][n] = __builtin_amdgcn_mfma_f32_16x16x32_bf16(af[m], bfr[n], acc[m][n], 0, 0, 0);
  }
  const float* b2p = b2 + (size_t)bs*TT;
  const float* xb = x + (((size_t)b*CC + mt*128)*SS + s)*TT;
  float* ob = out + (((size_t)b*CC + mt*128)*SS + s)*TT;
  #pragma unroll
  for (int n=0;n<4;n++) {
    int t = wn*64 + n*16 + lr;
    float bv = b2p[t];
    #pragma unroll
    for (int m=0;m<4;m++) {
      int rbase = wm*64 + m*16 + kg*4;
      #pragma unroll
      for (int j=0;j<4;j++) {
        size_t off = (size_t)(rbase+j)*(SS*TT) + t;
        ob[off] = acc[m][n][j] + bv + xb[off];
      }
    }
  }
}

extern "C" void kernel_launch(void* const* d_in, const int* in_sizes, int n_in,
                              void* d_out, int out_size, void* d_ws, size_t ws_size,
                              hipStream_t stream) {
  (void)in_sizes; (void)n_in; (void)out_size; (void)ws_size;
  const float* x     = (const float*)d_in[0];
  const float* gamma = (const float*)d_in[1];
  const float* beta  = (const float*)d_in[2];
  const float* keys1 = (const float*)d_in[3];
  const float* Wp1   = (const float*)d_in[4];
  const float* bp1   = (const float*)d_in[5];
  const float* keys2 = (const float*)d_in[6];
  const float* Wp2   = (const float*)d_in[7];
  const float* bp2   = (const float*)d_in[8];
  float* out = (float*)d_out;
  char* ws = (char*)d_ws;

  // ws layout (bytes):
  float* sumt   = (float*)(ws + 0);          // 128 f
  float* sumsq  = (float*)(ws + 512);        // 128 f
  float* p2acc  = (float*)(ws + 1024);       // 131072 f (atomic-accumulated)
  float* colsum = (float*)(ws + 525312);     // 65536 f
  float* b1     = (float*)(ws + 787456);     // 131072 f
  float* b2     = (float*)(ws + 1311744);    // 65536 f
  unsigned short* w1bf = (unsigned short*)(ws + 1573888);   // 16.7M bf16
  unsigned short* w2bf = (unsigned short*)(ws + 35128320);  // 16.7M bf16
  unsigned short* zbf  = (unsigned short*)(ws + 68682752);  // 67.1M bf16
  // total ws use: 202,900,480 bytes

  float* w1out = out + 33554432;
  float* w2out = out + 50331648;

  // zero the atomic accumulators (sumt, sumsq, p2acc are contiguous at front)
  hipMemsetAsync(ws, 0, 525312, stream);

  k1_stats <<<BS,   256, 0, stream>>>(x, sumt, sumsq, colsum);
  k2_route1<<<BS,   256, 0, stream>>>(sumt, sumsq, colsum, gamma, beta, keys1, Wp1, bp1,
                                      w1out, w1bf, b1);
  k3_gemm1 <<<BS*4, 256, 0, stream>>>(x, sumt, sumsq, gamma, beta, w1bf, b1, zbf, p2acc);
  k4_route2<<<BS,   256, 0, stream>>>(p2acc, keys2, Wp2, bp2, w2out, w2bf, b2);
  k5_gemm2 <<<BS*4, 256, 0, stream>>>(zbf, w2bf, b2, x, out);
}

// Round 2
// 372.268 us; speedup vs baseline: 1.0183x; 1.0183x over previous
//
#include <hip/hip_runtime.h>
#include <hip/hip_bf16.h>

#define BB 8
#define CC 512
#define SS 64
#define TT 128
#define DD 256
#define PP 8
#define BS (BB*SS)            // 512
#define NSTAT (BB*CC*SS)      // 262144
#define EPSV 1e-5f

typedef float f32x4 __attribute__((ext_vector_type(4)));
typedef __bf16 bf16x8 __attribute__((ext_vector_type(8)));

__device__ __forceinline__ unsigned short f2bf(float f) {
  unsigned u = __float_as_uint(f);
  u += 0x7FFFu + ((u >> 16) & 1u);
  return (unsigned short)(u >> 16);
}
__device__ __forceinline__ float bf2f(unsigned short h) {
  return __uint_as_float(((unsigned)h) << 16);
}

// ---- K1: BN stats (per-t sum/sumsq) + per-(b,s) column sums + bf16 stash of x ----
__global__ __launch_bounds__(256) void k1_stats(const float* __restrict__ x,
    float* __restrict__ sumt, float* __restrict__ sumsq, float* __restrict__ colsum,
    unsigned short* __restrict__ xbf) {
  int bs = blockIdx.x; int b = bs >> 6, s = bs & 63;
  const float* xb = x + ((size_t)b * CC * SS + s) * TT;
  unsigned short* xo = xbf + ((size_t)b * CC * SS + s) * TT;
  int tid = threadIdx.x;
  int t4 = tid & 31, coff = tid >> 5;
  float cs0=0,cs1=0,cs2=0,cs3=0, ss0=0,ss1=0,ss2=0,ss3=0;
  #pragma unroll 4
  for (int c = coff; c < CC; c += 8) {
    float4 v = *reinterpret_cast<const float4*>(xb + (size_t)c*(SS*TT) + t4*4);
    ushort4 o; o.x=f2bf(v.x); o.y=f2bf(v.y); o.z=f2bf(v.z); o.w=f2bf(v.w);
    *reinterpret_cast<ushort4*>(xo + (size_t)c*(SS*TT) + t4*4) = o;
    cs0 += v.x; cs1 += v.y; cs2 += v.z; cs3 += v.w;
    ss0 += v.x*v.x; ss1 += v.y*v.y; ss2 += v.z*v.z; ss3 += v.w*v.w;
  }
  __shared__ float4 redC[256];
  __shared__ float4 redS[256];
  redC[tid] = make_float4(cs0,cs1,cs2,cs3);
  redS[tid] = make_float4(ss0,ss1,ss2,ss3);
  __syncthreads();
  if (tid < 32) {
    #pragma unroll
    for (int j = 1; j < 8; j++) {
      float4 a = redC[tid + j*32], bq = redS[tid + j*32];
      cs0+=a.x; cs1+=a.y; cs2+=a.z; cs3+=a.w;
      ss0+=bq.x; ss1+=bq.y; ss2+=bq.z; ss3+=bq.w;
    }
    *reinterpret_cast<float4*>(colsum + (size_t)bs*TT + tid*4) = make_float4(cs0,cs1,cs2,cs3);
    atomicAdd(&sumt[tid*4+0], cs0); atomicAdd(&sumt[tid*4+1], cs1);
    atomicAdd(&sumt[tid*4+2], cs2); atomicAdd(&sumt[tid*4+3], cs3);
    atomicAdd(&sumsq[tid*4+0], ss0); atomicAdd(&sumsq[tid*4+1], ss1);
    atomicAdd(&sumsq[tid*4+2], ss2); atomicAdd(&sumsq[tid*4+3], ss3);
  }
}

// ---------------- K2: route 1 -> a1, W1 (fp32 out), b1 --------------------
__global__ __launch_bounds__(256) void k2_route1(
    const float* __restrict__ sumt, const float* __restrict__ sumsq,
    const float* __restrict__ colsum, const float* __restrict__ gamma,
    const float* __restrict__ beta, const float* __restrict__ keys1,
    const float* __restrict__ Wp1, const float* __restrict__ bp1,
    float* __restrict__ w1out, float* __restrict__ b1) {
  int bs = blockIdx.x, tid = threadIdx.x;
  __shared__ float a1s[PP];
  if (tid < 64) {
    float pv0, pv1;
    {
      int t = tid;
      float m = sumt[t] * (1.f/NSTAT);
      float var = sumsq[t]*(1.f/NSTAT) - m*m;
      float g = gamma[t] * rsqrtf(var + EPSV);
      pv0 = (colsum[(size_t)bs*TT + t]*(1.f/CC) - m)*g + beta[t];
    }
    {
      int t = tid + 64;
      float m = sumt[t] * (1.f/NSTAT);
      float var = sumsq[t]*(1.f/NSTAT) - m*m;
      float g = gamma[t] * rsqrtf(var + EPSV);
      pv1 = (colsum[(size_t)bs*TT + t]*(1.f/CC) - m)*g + beta[t];
    }
    float ssq = pv0*pv0 + pv1*pv1;
    #pragma unroll
    for (int off=32; off; off>>=1) ssq += __shfl_xor(ssq, off);
    float pn = sqrtf(ssq) + 1e-8f;
    float lg[PP];
    #pragma unroll
    for (int p=0;p<PP;p++) {
      float k0 = keys1[p*TT + tid], k1 = keys1[p*TT + tid + 64];
      float dot = pv0*k0 + pv1*k1;
      float kn = k0*k0 + k1*k1;
      #pragma unroll
      for (int off=32; off; off>>=1) { dot += __shfl_xor(dot,off); kn += __shfl_xor(kn,off); }
      lg[p] = dot / (pn * (sqrtf(kn) + 1e-8f));
    }
    if (tid == 0) {
      float mx = lg[0];
      #pragma unroll
      for (int p=1;p<PP;p++) mx = fmaxf(mx, lg[p]);
      float se = 0.f, e[PP];
      #pragma unroll
      for (int p=0;p<PP;p++){ e[p] = __expf(lg[p]-mx); se += e[p]; }
      float inv = 1.f/se;
      #pragma unroll
      for (int p=0;p<PP;p++) a1s[p] = e[p]*inv;
    }
  }
  __syncthreads();
  float a[PP];
  #pragma unroll
  for (int p=0;p<PP;p++) a[p]=a1s[p];
  const float4* wp = reinterpret_cast<const float4*>(Wp1);
  float4* wo = reinterpret_cast<float4*>(w1out + (size_t)bs*(DD*TT));
  for (int i=0;i<32;i++) {
    int idx = tid + i*256;
    float4 accv = make_float4(0.f,0.f,0.f,0.f);
    #pragma unroll
    for (int p=0;p<PP;p++) {
      float4 v = wp[p*8192 + idx];
      accv.x += a[p]*v.x; accv.y += a[p]*v.y; accv.z += a[p]*v.z; accv.w += a[p]*v.w;
    }
    wo[idx] = accv;
  }
  {
    float bacc = 0.f;
    #pragma unroll
    for (int p=0;p<PP;p++) bacc += a[p]*bp1[p*DD + tid];
    b1[(size_t)bs*DD + tid] = bacc;
  }
}

// ---- K3: GEMM1 (Z = relu(BN(x) @ W1^T + b1)) + pooled2 partials ----
__global__ __launch_bounds__(256) void k3_gemm1(
    const unsigned short* __restrict__ xbf, const float* __restrict__ sumt,
    const float* __restrict__ sumsq, const float* __restrict__ gamma,
    const float* __restrict__ beta, const float* __restrict__ w1out,
    const float* __restrict__ b1, unsigned short* __restrict__ zbf,
    float* __restrict__ p2acc) {
  int bid = blockIdx.x;
  int bs = bid >> 2, mt = bid & 3;
  int b = bs >> 6, s = bs & 63;
  __shared__ unsigned short lA[128*128];   // 32 KB, row stride 256 B, XOR-swizzled
  __shared__ unsigned short lB[256*128];   // 64 KB, row stride 256 B, XOR-swizzled
  __shared__ float mean_s[TT], g_s[TT], beta_s[TT];
  int tid = threadIdx.x;
  if (tid < TT) {
    float m = sumt[tid]*(1.f/NSTAT);
    float var = sumsq[tid]*(1.f/NSTAT) - m*m;
    mean_s[tid] = m;
    g_s[tid] = gamma[tid]*rsqrtf(var+EPSV);
    beta_s[tid] = beta[tid];
  }
  __syncthreads();
  char* lAc = reinterpret_cast<char*>(lA);
  char* lBc = reinterpret_cast<char*>(lB);
  // stage A (bf16 x -> BN -> bf16)
  const unsigned short* xb = xbf + (((size_t)b*CC + mt*128)*SS + s)*TT;
  #pragma unroll
  for (int i=0;i<16;i++) {
    int flat = tid + i*256;
    int r = flat >> 5, c4 = flat & 31;
    int t0 = c4*4;
    ushort4 v = *reinterpret_cast<const ushort4*>(xb + (size_t)r*(SS*TT) + t0);
    ushort4 o;
    o.x = f2bf((bf2f(v.x) - mean_s[t0+0])*g_s[t0+0] + beta_s[t0+0]);
    o.y = f2bf((bf2f(v.y) - mean_s[t0+1])*g_s[t0+1] + beta_s[t0+1]);
    o.z = f2bf((bf2f(v.z) - mean_s[t0+2])*g_s[t0+2] + beta_s[t0+2]);
    o.w = f2bf((bf2f(v.w) - mean_s[t0+3])*g_s[t0+3] + beta_s[t0+3]);
    unsigned addr = (unsigned)(r*256) + (((unsigned)(c4*8)) ^ (((unsigned)(r&7))<<4));
    *reinterpret_cast<ushort4*>(lAc + addr) = o;
  }
  // stage B (W1 fp32 -> bf16)
  const float* wsrc = w1out + (size_t)bs*(DD*TT);
  #pragma unroll
  for (int i=0;i<16;i++) {
    int flat = tid + i*256;
    int n = flat >> 4, ch = flat & 15;
    const float* src = wsrc + (size_t)n*TT + ch*8;
    float4 v0 = *reinterpret_cast<const float4*>(src);
    float4 v1 = *reinterpret_cast<const float4*>(src + 4);
    ushort4 o0, o1;
    o0.x=f2bf(v0.x); o0.y=f2bf(v0.y); o0.z=f2bf(v0.z); o0.w=f2bf(v0.w);
    o1.x=f2bf(v1.x); o1.y=f2bf(v1.y); o1.z=f2bf(v1.z); o1.w=f2bf(v1.w);
    unsigned addr = (unsigned)(n*256) + (((unsigned)(ch*16)) ^ (((unsigned)(n&7))<<4));
    *reinterpret_cast<ushort4*>(lBc + addr) = o0;
    *reinterpret_cast<ushort4*>(lBc + addr + 8) = o1;
  }
  __syncthreads();
  int wave = tid >> 6, lane = tid & 63;
  int wm = wave >> 1, wn = wave & 1;
  int lr = lane & 15, kg = lane >> 4;
  f32x4 zero = {0.f,0.f,0.f,0.f};
  f32x4 acc[4][8];
  #pragma unroll
  for (int m=0;m<4;m++)
    #pragma unroll
    for (int n=0;n<8;n++) acc[m][n] = zero;
  #pragma unroll
  for (int k0=0;k0<128;k0+=32) {
    bf16x8 af[4], bfr[8];
    #pragma unroll
    for (int m=0;m<4;m++) {
      int row = wm*64 + m*16 + lr;
      unsigned addr = (unsigned)(row*256) + (((unsigned)(k0*2 + kg*16)) ^ (((unsigned)(row&7))<<4));
      af[m] = *reinterpret_cast<const bf16x8*>(lAc + addr);
    }
    #pragma unroll
    for (int n=0;n<8;n++) {
      int row = wn*128 + n*16 + lr;
      unsigned addr = (unsigned)(row*256) + (((unsigned)(k0*2 + kg*16)) ^ (((unsigned)(row&7))<<4));
      bfr[n] = *reinterpret_cast<const bf16x8*>(lBc + addr);
    }
    #pragma unroll
    for (int m=0;m<4;m++)
      #pragma unroll
      for (int n=0;n<8;n++)
        acc[m][n] = __builtin_amdgcn_mfma_f32_16x16x32_bf16(af[m], bfr[n], acc[m][n], 0, 0, 0);
  }
  // epilogue: +b1, relu, store Z bf16, pooled2 partial sums
  const float* b1p = b1 + (size_t)bs*DD;
  unsigned short* zb = zbf + (((size_t)b*CC + mt*128)*SS + s)*DD;
  float* p2p = p2acc + (size_t)bs*DD;
  #pragma unroll
  for (int n=0;n<8;n++) {
    int d = wn*128 + n*16 + lr;
    float bv = b1p[d];
    float csum = 0.f;
    #pragma unroll
    for (int m=0;m<4;m++) {
      int rbase = wm*64 + m*16 + kg*4;
      #pragma unroll
      for (int j=0;j<4;j++) {
        float v = fmaxf(acc[m][n][j] + bv, 0.f);
        zb[(size_t)(rbase+j)*(SS*DD) + d] = f2bf(v);
        csum += v;
      }
    }
    csum += __shfl_xor(csum, 16);
    csum += __shfl_xor(csum, 32);
    if (kg == 0) atomicAdd(&p2p[d], csum);
  }
}

// ---------------- K4: route 2 -> a2, W2 (fp32 out), b2 --------------------
__global__ __launch_bounds__(256) void k4_route2(
    const float* __restrict__ p2acc, const float* __restrict__ keys2,
    const float* __restrict__ Wp2, const float* __restrict__ bp2,
    float* __restrict__ w2out, float* __restrict__ b2) {
  int bs = blockIdx.x, tid = threadIdx.x;
  __shared__ float a2s[PP];
  if (tid < 64) {
    float pv[4]; float ssq = 0.f;
    #pragma unroll
    for (int j=0;j<4;j++) {
      int d = tid + 64*j;
      pv[j] = p2acc[(size_t)bs*DD + d] * (1.f/CC);
      ssq += pv[j]*pv[j];
    }
    #pragma unroll
    for (int off=32; off; off>>=1) ssq += __shfl_xor(ssq, off);
    float pn = sqrtf(ssq) + 1e-8f;
    float lg[PP];
    #pragma unroll
    for (int p=0;p<PP;p++) {
      float dot = 0.f, kn = 0.f;
      #pragma unroll
      for (int j=0;j<4;j++) {
        int d = tid + 64*j;
        float kv = keys2[p*DD + d];
        dot += pv[j]*kv; kn += kv*kv;
      }
      #pragma unroll
      for (int off=32; off; off>>=1) { dot += __shfl_xor(dot,off); kn += __shfl_xor(kn,off); }
      lg[p] = dot / (pn * (sqrtf(kn)+1e-8f));
    }
    if (tid == 0) {
      float mx = lg[0];
      #pragma unroll
      for (int p=1;p<PP;p++) mx = fmaxf(mx,lg[p]);
      float se=0.f, e[PP];
      #pragma unroll
      for (int p=0;p<PP;p++){ e[p]=__expf(lg[p]-mx); se+=e[p]; }
      float inv = 1.f/se;
      #pragma unroll
      for (int p=0;p<PP;p++) a2s[p]=e[p]*inv;
    }
  }
  __syncthreads();
  float a[PP];
  #pragma unroll
  for (int p=0;p<PP;p++) a[p]=a2s[p];
  const float4* wp = reinterpret_cast<const float4*>(Wp2);
  float4* wo = reinterpret_cast<float4*>(w2out + (size_t)bs*(TT*DD));
  for (int i=0;i<32;i++) {
    int idx = tid + i*256;
    float4 accv = make_float4(0.f,0.f,0.f,0.f);
    #pragma unroll
    for (int p=0;p<PP;p++) {
      float4 v = wp[p*8192 + idx];
      accv.x += a[p]*v.x; accv.y += a[p]*v.y; accv.z += a[p]*v.z; accv.w += a[p]*v.w;
    }
    wo[idx] = accv;
  }
  if (tid < TT) {
    float bacc = 0.f;
    #pragma unroll
    for (int p=0;p<PP;p++) bacc += a[p]*bp2[p*TT + tid];
    b2[(size_t)bs*TT + tid] = bacc;
  }
}

// ---------------- K5: GEMM2 (out = x + Z @ W2^T + b2) -------------------------------
__global__ __launch_bounds__(256) void k5_gemm2(
    const unsigned short* __restrict__ zbf, const float* __restrict__ w2out,
    const float* __restrict__ b2, const unsigned short* __restrict__ xbf,
    float* __restrict__ out) {
  int bid = blockIdx.x;
  int bs = bid >> 2, mt = bid & 3;
  int b = bs >> 6, s = bs & 63;
  __shared__ unsigned short lA[128*256];   // 64 KB, row stride 512 B
  __shared__ unsigned short lB[128*256];   // 64 KB, row stride 512 B
  int tid = threadIdx.x;
  char* lAc = reinterpret_cast<char*>(lA);
  char* lBc = reinterpret_cast<char*>(lB);
  const unsigned short* za = zbf + (((size_t)b*CC + mt*128)*SS + s)*DD;
  #pragma unroll
  for (int i=0;i<16;i++) {
    int flat = tid + i*256;
    int r = flat >> 5, ch = flat & 31;
    uint4 v = *reinterpret_cast<const uint4*>(za + (size_t)r*(SS*DD) + ch*8);
    unsigned addr = (unsigned)(r*512) + (((unsigned)(ch*16)) ^ (((unsigned)(r&7))<<4));
    *reinterpret_cast<uint4*>(lAc + addr) = v;
  }
  const float* wsrc = w2out + (size_t)bs*(TT*DD);
  #pragma unroll
  for (int i=0;i<16;i++) {
    int flat = tid + i*256;
    int r = flat >> 5, ch = flat & 31;
    const float* src = wsrc + (size_t)flat*8;
    float4 v0 = *reinterpret_cast<const float4*>(src);
    float4 v1 = *reinterpret_cast<const float4*>(src + 4);
    ushort4 o0, o1;
    o0.x=f2bf(v0.x); o0.y=f2bf(v0.y); o0.z=f2bf(v0.z); o0.w=f2bf(v0.w);
    o1.x=f2bf(v1.x); o1.y=f2bf(v1.y); o1.z=f2bf(v1.z); o1.w=f2bf(v1.w);
    unsigned addr = (unsigned)(r*512) + (((unsigned)(ch*16)) ^ (((unsigned)(r&7))<<4));
    *reinterpret_cast<ushort4*>(lBc + addr) = o0;
    *reinterpret_cast<ushort4*>(lBc + addr + 8) = o1;
  }
  __syncthreads();
  int wave = tid >> 6, lane = tid & 63;
  int wm = wave >> 1, wn = wave & 1;
  int lr = lane & 15, kg = lane >> 4;
  f32x4 zero = {0.f,0.f,0.f,0.f};
  f32x4 acc[4][4];
  #pragma unroll
  for (int m=0;m<4;m++)
    #pragma unroll
    for (int n=0;n<4;n++) acc[m][n] = zero;
  #pragma unroll
  for (int k0=0;k0<256;k0+=32) {
    bf16x8 af[4], bfr[4];
    #pragma unroll
    for (int m=0;m<4;m++) {
      int row = wm*64 + m*16 + lr;
      unsigned addr = (unsigned)(row*512) + (((unsigned)(k0*2 + kg*16)) ^ (((unsigned)(row&7))<<4));
      af[m] = *reinterpret_cast<const bf16x8*>(lAc + addr);
    }
    #pragma unroll
    for (int n=0;n<4;n++) {
      int row = wn*64 + n*16 + lr;
      unsigned addr = (unsigned)(row*512) + (((unsigned)(k0*2 + kg*16)) ^ (((unsigned)(row&7))<<4));
      bfr[n] = *reinterpret_cast<const bf16x8*>(lBc + addr);
    }
    #pragma unroll
    for (int m=0;m<4;m++)
      #pragma unroll
      for (int n=0;n<4;n++)
        acc[m][n] = __builtin_amdgcn_mfma_f32_16x16x32_bf16(af[m], bfr[n], acc[m][n], 0, 0, 0);
  }
  const float* b2p = b2 + (size_t)bs*TT;
  const unsigned short* xb = xbf + (((size_t)b*CC + mt*128)*SS + s)*TT;
  float* ob = out + (((size_t)b*CC + mt*128)*SS + s)*TT;
  #pragma unroll
  for (int n=0;n<4;n++) {
    int t = wn*64 + n*16 + lr;
    float bv = b2p[t];
    #pragma unroll
    for (int m=0;m<4;m++) {
      int rbase = wm*64 + m*16 + kg*4;
      #pragma unroll
      for (int j=0;j<4;j++) {
        size_t off = (size_t)(rbase+j)*(SS*TT) + t;
        ob[off] = acc[m][n][j] + bv + bf2f(xb[off]);
      }
    }
  }
}

extern "C" void kernel_launch(void* const* d_in, const int* in_sizes, int n_in,
                              void* d_out, int out_size, void* d_ws, size_t ws_size,
                              hipStream_t stream) {
  (void)in_sizes; (void)n_in; (void)out_size; (void)ws_size;
  const float* x     = (const float*)d_in[0];
  const float* gamma = (const float*)d_in[1];
  const float* beta  = (const float*)d_in[2];
  const float* keys1 = (const float*)d_in[3];
  const float* Wp1   = (const float*)d_in[4];
  const float* bp1   = (const float*)d_in[5];
  const float* keys2 = (const float*)d_in[6];
  const float* Wp2   = (const float*)d_in[7];
  const float* bp2   = (const float*)d_in[8];
  float* out = (float*)d_out;
  char* ws = (char*)d_ws;

  // ws layout (bytes):
  float* sumt   = (float*)(ws + 0);          // 128 f
  float* sumsq  = (float*)(ws + 512);        // 128 f
  float* p2acc  = (float*)(ws + 1024);       // 131072 f (atomic-accumulated)
  float* colsum = (float*)(ws + 525312);     // 65536 f
  float* b1     = (float*)(ws + 787456);     // 131072 f
  float* b2     = (float*)(ws + 1311744);    // 65536 f
  unsigned short* xbf = (unsigned short*)(ws + 1573888);   // 33.5M bf16 = 67.1 MB
  unsigned short* zbf = (unsigned short*)(ws + 68682752);  // 67.1M bf16 = 134.2 MB
  // total ws use: 202,900,480 bytes

  float* w1out = out + 33554432;
  float* w2out = out + 50331648;

  // zero the atomic accumulators (sumt, sumsq, p2acc are contiguous at front)
  hipMemsetAsync(ws, 0, 525312, stream);

  k1_stats <<<BS,   256, 0, stream>>>(x, sumt, sumsq, colsum, xbf);
  k2_route1<<<BS,   256, 0, stream>>>(sumt, sumsq, colsum, gamma, beta, keys1, Wp1, bp1,
                                      w1out, b1);
  k3_gemm1 <<<BS*4, 256, 0, stream>>>(xbf, sumt, sumsq, gamma, beta, w1out, b1, zbf, p2acc);
  k4_route2<<<BS,   256, 0, stream>>>(p2acc, keys2, Wp2, bp2, w2out, b2);
  k5_gemm2 <<<BS*4, 256, 0, stream>>>(zbf, w2out, b2, xbf, out);
}